// Round 4
// baseline (841.187 us; speedup 1.0000x reference)
//
#include <hip/hip_runtime.h>
#include <stdint.h>

#define N_NODES 20000
#define N_EDGES 320000
#define N_BATCH 32
#define DIM     128

typedef short v8s __attribute__((ext_vector_type(8)));
typedef float v4f __attribute__((ext_vector_type(4)));

static inline int cdiv(int a, int b){ return (a + b - 1) / b; }

__device__ __forceinline__ float bf_lo(uint32_t u){ return __uint_as_float(u << 16); }
__device__ __forceinline__ float bf_hi(uint32_t u){ return __uint_as_float(u & 0xffff0000u); }
__device__ __forceinline__ uint32_t f2bf(float f){            // RNE bf16 (finite inputs)
  uint32_t x = __float_as_uint(f);
  return (x + 0x7fffu + ((x >> 16) & 1u)) >> 16;
}
__device__ __forceinline__ uint32_t packbf2(float a, float b){ return f2bf(a) | (f2bf(b) << 16); }

// ---------------- setup kernels ----------------

__global__ void k_zero(uint32_t* p, int n){
  int i = blockIdx.x * 256 + threadIdx.x;
  if (i < n) p[i] = 0u;
}

__global__ void k_hist(const int* __restrict__ ei, uint32_t* __restrict__ hist){
  int e = blockIdx.x * 256 + threadIdx.x;
  if (e < N_EDGES){
    int d = ei[N_EDGES + e];
    atomicAdd(&hist[d], 1u);
  }
}

// single-block exclusive scan of hist -> row_start; also deg-derived dinv, c-init
__global__ void k_scan(const uint32_t* __restrict__ hist, uint32_t* __restrict__ row_start,
                       float* __restrict__ dinv, float* __restrict__ cw){
  __shared__ uint32_t part[1024];
  const int t = threadIdx.x;
  const int base = t * 20;                       // 1024*20 = 20480 >= 20000
  uint32_t cnt[20];
  uint32_t s = 0;
  #pragma unroll
  for (int i = 0; i < 20; i++){
    int idx = base + i;
    uint32_t v = (idx < N_NODES) ? hist[idx] : 0u;
    cnt[i] = v; s += v;
  }
  part[t] = s;
  __syncthreads();
  for (int off = 1; off < 1024; off <<= 1){      // inclusive Hillis-Steele
    uint32_t v = part[t];
    uint32_t add = (t >= off) ? part[t - off] : 0u;
    __syncthreads();
    part[t] = v + add;
    __syncthreads();
  }
  uint32_t run = (t > 0) ? part[t - 1] : 0u;     // exclusive prefix
  #pragma unroll
  for (int i = 0; i < 20; i++){
    int idx = base + i;
    if (idx < N_NODES){
      row_start[idx] = run;
      float deg = (float)cnt[i] + 1.0f;
      dinv[idx] = rsqrtf(deg);
      cw[idx]   = 1.0f / deg;                    // self_norm; edge terms added by k_edge
      run += cnt[i];
    }
  }
}

__global__ void k_edge(const int* __restrict__ ei, const uint32_t* __restrict__ row_start,
                       uint32_t* __restrict__ cursor, const float* __restrict__ dinv,
                       float* __restrict__ cw, int2* __restrict__ emeta){
  int e = blockIdx.x * 256 + threadIdx.x;
  if (e >= N_EDGES) return;
  int s = ei[e];
  int d = ei[N_EDGES + e];
  float w = dinv[s] * dinv[d];
  atomicAdd(&cw[s], w);
  uint32_t off = atomicAdd(&cursor[d], 1u);
  uint32_t pos = row_start[d] + off;
  emeta[pos] = make_int2(s, __float_as_int(w));
}

// W1 fp32 [k][f] -> bf16 frag-packed: W1P[((k>>3)*128 + f)*8 + (k&7)]
__global__ void k_w1pack(const float* __restrict__ W1, uint16_t* __restrict__ W1P){
  int i = blockIdx.x * 256 + threadIdx.x;
  if (i >= 16 * 128 * 8) return;
  int e = i & 7, f = (i >> 3) & 127, q = i >> 10;
  int k = q * 8 + e;
  W1P[i] = (uint16_t)f2bf(W1[k * 128 + f]);
}

// fp32 -> packed bf16 (2 per u32), grid-stride
__global__ void k_cvt(const float2* __restrict__ x, uint32_t* __restrict__ xb, int n_u32){
  int i = blockIdx.x * 256 + threadIdx.x;
  int stride = gridDim.x * 256;
  for (; i < n_u32; i += stride){
    float2 v = x[i];
    xb[i] = packbf2(v.x, v.y);
  }
}

// ---------------- phase A: y = (A_hat x), bf16 in/out, fp32 accum ----------------
// one wave per (dst node, batch); lane holds feature pair k = 2*lane, 2*lane+1
__global__ void k_agg(const uint32_t* __restrict__ xb, uint32_t* __restrict__ yb,
                      const int2* __restrict__ emeta, const uint32_t* __restrict__ row_start,
                      const uint32_t* __restrict__ hist, const float* __restrict__ dinv){
  int w = threadIdx.x >> 6, lane = threadIdx.x & 63;
  int n = blockIdx.x * 4 + w;
  if (n >= N_NODES) return;
  uint32_t bl = blockIdx.y;
  uint32_t rowbase = bl * (uint32_t)N_NODES * 64u;

  float di = dinv[n];
  float self = di * di;
  uint32_t u = xb[rowbase + (uint32_t)n * 64u + lane];
  float a0 = self * bf_lo(u);
  float a1 = self * bf_hi(u);

  uint32_t rs  = (uint32_t)__builtin_amdgcn_readfirstlane((int)row_start[n]);
  uint32_t cnt = (uint32_t)__builtin_amdgcn_readfirstlane((int)hist[n]);
  for (uint32_t i = 0; i < cnt; i++){
    int2 m = emeta[rs + i];
    float wgt = __int_as_float(m.y);
    uint32_t v = xb[rowbase + (uint32_t)m.x * 64u + lane];
    a0 = fmaf(wgt, bf_lo(v), a0);
    a1 = fmaf(wgt, bf_hi(v), a1);
  }
  yb[rowbase + (uint32_t)n * 64u + lane] = packbf2(a0, a1);
}

// ---------------- phase B: S[b,f] += sum_n c[n]*relu(y[b,n,:]·W1[:,f] + b1[f]) ----------------
// 4 waves/block; each wave: W1 fully in registers (32 B-frags), loops 8 n-tiles of 16 rows
__global__ __launch_bounds__(256) void k_gemm(const uint16_t* __restrict__ y,
                                              const uint16_t* __restrict__ W1P,
                                              const float* __restrict__ b1,
                                              const float* __restrict__ cw,
                                              float* __restrict__ S, int b_global0){
  const int w = threadIdx.x >> 6, lane = threadIdx.x & 63;
  const int l15 = lane & 15, q = lane >> 4;
  const int bl = blockIdx.y;

  // B-frags: lane l, elem e -> W1[k][ft*16 + l15], k = q32*32 + q*8 + e  (same k-map as A)
  v8s bfr[4][8];
  #pragma unroll
  for (int q32 = 0; q32 < 4; q32++)
    #pragma unroll
    for (int ft = 0; ft < 8; ft++)
      bfr[q32][ft] = *reinterpret_cast<const v8s*>(W1P + ((q32 * 4 + q) * 128 + ft * 16 + l15) * 8);

  float b1v[8];
  #pragma unroll
  for (int ft = 0; ft < 8; ft++) b1v[ft] = b1[ft * 16 + l15];

  float sacc[8] = {0.f,0.f,0.f,0.f,0.f,0.f,0.f,0.f};

  const int NT = N_NODES / 16;                   // 1250 full tiles
  int tile0 = (blockIdx.x * 4 + w) * 8;
  for (int t = 0; t < 8; t++){
    int tile = tile0 + t;
    if (tile >= NT) break;
    int n0 = tile * 16;
    const uint16_t* yrow = y + ((size_t)bl * N_NODES + n0 + l15) * DIM + q * 8;
    v8s a0 = *reinterpret_cast<const v8s*>(yrow);
    v8s a1 = *reinterpret_cast<const v8s*>(yrow + 32);
    v8s a2 = *reinterpret_cast<const v8s*>(yrow + 64);
    v8s a3 = *reinterpret_cast<const v8s*>(yrow + 96);

    v4f acc[8];
    #pragma unroll
    for (int ft = 0; ft < 8; ft++) acc[ft] = (v4f){0.f,0.f,0.f,0.f};
    #pragma unroll
    for (int ft = 0; ft < 8; ft++) acc[ft] = __builtin_amdgcn_mfma_f32_16x16x32_bf16(a0, bfr[0][ft], acc[ft], 0, 0, 0);
    #pragma unroll
    for (int ft = 0; ft < 8; ft++) acc[ft] = __builtin_amdgcn_mfma_f32_16x16x32_bf16(a1, bfr[1][ft], acc[ft], 0, 0, 0);
    #pragma unroll
    for (int ft = 0; ft < 8; ft++) acc[ft] = __builtin_amdgcn_mfma_f32_16x16x32_bf16(a2, bfr[2][ft], acc[ft], 0, 0, 0);
    #pragma unroll
    for (int ft = 0; ft < 8; ft++) acc[ft] = __builtin_amdgcn_mfma_f32_16x16x32_bf16(a3, bfr[3][ft], acc[ft], 0, 0, 0);

    // epilogue: + b1, relu, * c[row], accumulate. D: row = n0 + q*4 + r, col = ft*16 + l15
    float4 cvv = *reinterpret_cast<const float4*>(cw + n0 + q * 4);
    float cvr[4] = {cvv.x, cvv.y, cvv.z, cvv.w};
    #pragma unroll
    for (int ft = 0; ft < 8; ft++){
      #pragma unroll
      for (int r = 0; r < 4; r++){
        float v = acc[ft][r] + b1v[ft];
        v = fmaxf(v, 0.0f);
        sacc[ft] = fmaf(v, cvr[r], sacc[ft]);
      }
    }
  }

  // reduce over q-groups (rows) -> col sums, then one atomic per (f)
  #pragma unroll
  for (int ft = 0; ft < 8; ft++){
    float v = sacc[ft];
    v += __shfl_xor(v, 16);
    v += __shfl_xor(v, 32);
    if (lane < 16) atomicAdd(&S[(b_global0 + bl) * DIM + ft * 16 + lane], v);
  }
}

// ---------------- final: out[b,f] = (S[b,:]/N)·W2[:,f] + b2[f] ----------------
__global__ void k_final(const float* __restrict__ S, const float* __restrict__ W2,
                        const float* __restrict__ b2, float* __restrict__ out){
  int i = blockIdx.x * 256 + threadIdx.x;
  if (i >= N_BATCH * DIM) return;
  int b = i >> 7, f = i & 127;
  float o = 0.0f;
  const float invN = 1.0f / (float)N_NODES;
  #pragma unroll 4
  for (int k = 0; k < 128; k++)
    o = fmaf(S[b * 128 + k], W2[k * 128 + f], o);
  out[i] = fmaf(o, invN, b2[f]);
}

// ---------------- host ----------------

extern "C" void kernel_launch(void* const* d_in, const int* in_sizes, int n_in,
                              void* d_out, int out_size, void* d_ws, size_t ws_size,
                              hipStream_t stream){
  const float* gene = (const float*)d_in[0];
  const int*   ei   = (const int*)d_in[1];
  const float* W1   = (const float*)d_in[2];
  const float* b1   = (const float*)d_in[3];
  const float* W2   = (const float*)d_in[4];
  const float* b2   = (const float*)d_in[5];
  float* out = (float*)d_out;

  char* base = (char*)d_ws;
  size_t off = 0;
  auto take = [&](size_t bytes)->char*{
    char* p = base + off;
    off = (off + bytes + 255) & ~(size_t)255;
    return p;
  };

  // zero zone: hist (N+1) | cursor (N) | S (B*128 f32)  -- one contiguous zero pass
  const int ZWORDS = (N_NODES + 1) + N_NODES + N_BATCH * DIM;
  uint32_t* zzone  = (uint32_t*)take((size_t)ZWORDS * 4);
  uint32_t* hist   = zzone;
  uint32_t* cursor = zzone + (N_NODES + 1);
  float*    S      = (float*)(zzone + (N_NODES + 1) + N_NODES);

  uint32_t* row_start = (uint32_t*)take((size_t)N_NODES * 4);
  float*    dinv      = (float*)take((size_t)N_NODES * 4);
  float*    cw        = (float*)take((size_t)N_NODES * 4);
  int2*     emeta     = (int2*)take((size_t)N_EDGES * 8);
  uint16_t* W1P       = (uint16_t*)take((size_t)16 * 128 * 8 * 2);

  // batch-chunked x/y bf16 buffers sized to fit ws
  const size_t per_batch = (size_t)N_NODES * DIM * 2;   // 5.12 MB
  size_t remain = (ws_size > off) ? (ws_size - off) : 0;
  int C = (int)(remain / (2 * per_batch));
  if (C < 1) C = 1;
  if (C > N_BATCH) C = N_BATCH;
  uint32_t* xb = (uint32_t*)take(per_batch * C);
  uint32_t* yb = (uint32_t*)take(per_batch * C);

  k_zero<<<cdiv(ZWORDS, 256), 256, 0, stream>>>(zzone, ZWORDS);
  k_hist<<<cdiv(N_EDGES, 256), 256, 0, stream>>>(ei, hist);
  k_scan<<<1, 1024, 0, stream>>>(hist, row_start, dinv, cw);
  k_edge<<<cdiv(N_EDGES, 256), 256, 0, stream>>>(ei, row_start, cursor, dinv, cw, emeta);
  k_w1pack<<<64, 256, 0, stream>>>(W1, W1P);

  for (int b0 = 0; b0 < N_BATCH; b0 += C){
    int Cb = (N_BATCH - b0 < C) ? (N_BATCH - b0) : C;
    int nu = Cb * N_NODES * (DIM / 2);
    k_cvt<<<cdiv(nu, 2048), 256, 0, stream>>>(((const float2*)gene) + (size_t)b0 * N_NODES * (DIM / 2), xb, nu);
    k_agg<<<dim3(N_NODES / 4, Cb), 256, 0, stream>>>(xb, yb, emeta, row_start, hist, dinv);
    k_gemm<<<dim3(cdiv(N_NODES / 16, 32), Cb), 256, 0, stream>>>((const uint16_t*)yb, W1P, b1, cw, S, b0);
  }

  k_final<<<cdiv(N_BATCH * DIM, 256), 256, 0, stream>>>(S, W2, b2, out);
}

// Round 5
// 566.428 us; speedup vs baseline: 1.4851x; 1.4851x over previous
//
#include <hip/hip_runtime.h>
#include <stdint.h>

#define N_NODES 20000
#define N_EDGES 320000
#define N_BATCH 32
#define DIM     128

typedef short v8s __attribute__((ext_vector_type(8)));
typedef float v4f __attribute__((ext_vector_type(4)));

static inline int cdiv(int a, int b){ return (a + b - 1) / b; }

__device__ __forceinline__ float bf_lo(uint32_t u){ return __uint_as_float(u << 16); }
__device__ __forceinline__ float bf_hi(uint32_t u){ return __uint_as_float(u & 0xffff0000u); }
__device__ __forceinline__ uint32_t f2bf(float f){            // RNE bf16 (finite inputs)
  uint32_t x = __float_as_uint(f);
  return (x + 0x7fffu + ((x >> 16) & 1u)) >> 16;
}
__device__ __forceinline__ uint32_t packbf2(float a, float b){ return f2bf(a) | (f2bf(b) << 16); }

// ---------------- setup kernels ----------------

__global__ void k_zero(uint32_t* p, int n){
  int i = blockIdx.x * 256 + threadIdx.x;
  if (i < n) p[i] = 0u;
}

__global__ void k_hist(const int* __restrict__ ei, uint32_t* __restrict__ hist){
  int e = blockIdx.x * 256 + threadIdx.x;
  if (e < N_EDGES){
    int d = ei[N_EDGES + e];
    atomicAdd(&hist[d], 1u);
  }
}

// single-block exclusive scan of hist -> row_start; also deg-derived dinv, c-init
__global__ void k_scan(const uint32_t* __restrict__ hist, uint32_t* __restrict__ row_start,
                       float* __restrict__ dinv, float* __restrict__ cw){
  __shared__ uint32_t part[1024];
  const int t = threadIdx.x;
  const int base = t * 20;                       // 1024*20 = 20480 >= 20000
  uint32_t cnt[20];
  uint32_t s = 0;
  #pragma unroll
  for (int i = 0; i < 20; i++){
    int idx = base + i;
    uint32_t v = (idx < N_NODES) ? hist[idx] : 0u;
    cnt[i] = v; s += v;
  }
  part[t] = s;
  __syncthreads();
  for (int off = 1; off < 1024; off <<= 1){      // inclusive Hillis-Steele
    uint32_t v = part[t];
    uint32_t add = (t >= off) ? part[t - off] : 0u;
    __syncthreads();
    part[t] = v + add;
    __syncthreads();
  }
  uint32_t run = (t > 0) ? part[t - 1] : 0u;     // exclusive prefix
  #pragma unroll
  for (int i = 0; i < 20; i++){
    int idx = base + i;
    if (idx < N_NODES){
      row_start[idx] = run;
      float deg = (float)cnt[i] + 1.0f;
      dinv[idx] = rsqrtf(deg);
      cw[idx]   = 1.0f / deg;                    // self_norm; edge terms added by k_edge
      run += cnt[i];
    }
  }
}

__global__ void k_edge(const int* __restrict__ ei, const uint32_t* __restrict__ row_start,
                       uint32_t* __restrict__ cursor, const float* __restrict__ dinv,
                       float* __restrict__ cw, int2* __restrict__ emeta){
  int e = blockIdx.x * 256 + threadIdx.x;
  if (e >= N_EDGES) return;
  int s = ei[e];
  int d = ei[N_EDGES + e];
  float w = dinv[s] * dinv[d];
  atomicAdd(&cw[s], w);
  uint32_t off = atomicAdd(&cursor[d], 1u);
  uint32_t pos = row_start[d] + off;
  emeta[pos] = make_int2(s, __float_as_int(w));
}

// W1 fp32 [k][f] -> bf16 frag-packed: W1P[((k>>3)*128 + f)*8 + (k&7)]
__global__ void k_w1pack(const float* __restrict__ W1, uint16_t* __restrict__ W1P){
  int i = blockIdx.x * 256 + threadIdx.x;
  if (i >= 16 * 128 * 8) return;
  int e = i & 7, f = (i >> 3) & 127, q = i >> 10;
  int k = q * 8 + e;
  W1P[i] = (uint16_t)f2bf(W1[k * 128 + f]);
}

// fp32 -> packed bf16 (2 per u32), grid-stride
__global__ void k_cvt(const float2* __restrict__ x, uint32_t* __restrict__ xb, int n_u32){
  int i = blockIdx.x * 256 + threadIdx.x;
  int stride = gridDim.x * 256;
  for (; i < n_u32; i += stride){
    float2 v = x[i];
    xb[i] = packbf2(v.x, v.y);
  }
}

// ---------------- phase A: y = (A_hat x), bf16 in/out, fp32 accum ----------------
// one wave per (dst node, batch); lane holds feature pair k = 2*lane, 2*lane+1.
// Edge metadata vector-loaded once per 64-edge chunk, broadcast via shfl (uniform
// index -> readlane); gathers unrolled x4 with independent accumulators so each
// wave keeps 4x256B loads in flight (latency -> BW bound).
__global__ __launch_bounds__(256) void k_agg(const uint32_t* __restrict__ xb, uint32_t* __restrict__ yb,
                      const int2* __restrict__ emeta, const uint32_t* __restrict__ row_start,
                      const uint32_t* __restrict__ hist, const float* __restrict__ dinv){
  int w = threadIdx.x >> 6, lane = threadIdx.x & 63;
  int n = blockIdx.x * 4 + w;
  if (n >= N_NODES) return;
  uint32_t bl = blockIdx.y;
  uint32_t rowbase = bl * (uint32_t)N_NODES * 64u;

  float di = dinv[n];
  float self = di * di;
  uint32_t u = xb[rowbase + (uint32_t)n * 64u + lane];
  float a0 = self * bf_lo(u), a1 = self * bf_hi(u);
  float b0 = 0.f, b1 = 0.f;
  float c0 = 0.f, c1 = 0.f;
  float d0 = 0.f, d1 = 0.f;

  uint32_t rs  = (uint32_t)__builtin_amdgcn_readfirstlane((int)row_start[n]);
  uint32_t cnt = (uint32_t)__builtin_amdgcn_readfirstlane((int)hist[n]);

  const uint32_t* xrow = xb + rowbase + (uint32_t)lane;   // + src*64

  for (uint32_t base = 0; base < cnt; base += 64u){
    uint32_t lim = cnt - base; if (lim > 64u) lim = 64u;   // edges in this chunk
    uint32_t li = (uint32_t)lane; if (li >= lim) li = lim - 1u;
    int2 m = emeta[rs + base + li];                        // one coalesced 512B load

    uint32_t i = 0;
    for (; i + 4u <= lim; i += 4u){
      int s0 = __shfl(m.x, (int)i);
      int s1 = __shfl(m.x, (int)(i + 1u));
      int s2 = __shfl(m.x, (int)(i + 2u));
      int s3 = __shfl(m.x, (int)(i + 3u));
      float w0 = __int_as_float(__shfl(m.y, (int)i));
      float w1 = __int_as_float(__shfl(m.y, (int)(i + 1u)));
      float w2 = __int_as_float(__shfl(m.y, (int)(i + 2u)));
      float w3 = __int_as_float(__shfl(m.y, (int)(i + 3u)));
      uint32_t v0 = xrow[(uint32_t)s0 * 64u];
      uint32_t v1 = xrow[(uint32_t)s1 * 64u];
      uint32_t v2 = xrow[(uint32_t)s2 * 64u];
      uint32_t v3 = xrow[(uint32_t)s3 * 64u];
      a0 = fmaf(w0, bf_lo(v0), a0); a1 = fmaf(w0, bf_hi(v0), a1);
      b0 = fmaf(w1, bf_lo(v1), b0); b1 = fmaf(w1, bf_hi(v1), b1);
      c0 = fmaf(w2, bf_lo(v2), c0); c1 = fmaf(w2, bf_hi(v2), c1);
      d0 = fmaf(w3, bf_lo(v3), d0); d1 = fmaf(w3, bf_hi(v3), d1);
    }
    for (; i < lim; i++){
      int s0 = __shfl(m.x, (int)i);
      float w0 = __int_as_float(__shfl(m.y, (int)i));
      uint32_t v0 = xrow[(uint32_t)s0 * 64u];
      a0 = fmaf(w0, bf_lo(v0), a0); a1 = fmaf(w0, bf_hi(v0), a1);
    }
  }

  a0 = (a0 + b0) + (c0 + d0);
  a1 = (a1 + b1) + (c1 + d1);
  yb[rowbase + (uint32_t)n * 64u + lane] = packbf2(a0, a1);
}

// ---------------- phase B: S[b,f] += sum_n c[n]*relu(y[b,n,:]·W1[:,f] + b1[f]) ----------------
// 4 waves/block; each wave: W1 fully in registers (32 B-frags), loops 8 n-tiles of 16 rows
__global__ __launch_bounds__(256) void k_gemm(const uint16_t* __restrict__ y,
                                              const uint16_t* __restrict__ W1P,
                                              const float* __restrict__ b1,
                                              const float* __restrict__ cw,
                                              float* __restrict__ S, int b_global0){
  const int w = threadIdx.x >> 6, lane = threadIdx.x & 63;
  const int l15 = lane & 15, q = lane >> 4;
  const int bl = blockIdx.y;

  // B-frags: lane l, elem e -> W1[k][ft*16 + l15], k = q32*32 + q*8 + e  (same k-map as A)
  v8s bfr[4][8];
  #pragma unroll
  for (int q32 = 0; q32 < 4; q32++)
    #pragma unroll
    for (int ft = 0; ft < 8; ft++)
      bfr[q32][ft] = *reinterpret_cast<const v8s*>(W1P + ((q32 * 4 + q) * 128 + ft * 16 + l15) * 8);

  float b1v[8];
  #pragma unroll
  for (int ft = 0; ft < 8; ft++) b1v[ft] = b1[ft * 16 + l15];

  float sacc[8] = {0.f,0.f,0.f,0.f,0.f,0.f,0.f,0.f};

  const int NT = N_NODES / 16;                   // 1250 full tiles
  int tile0 = (blockIdx.x * 4 + w) * 8;
  for (int t = 0; t < 8; t++){
    int tile = tile0 + t;
    if (tile >= NT) break;
    int n0 = tile * 16;
    const uint16_t* yrow = y + ((size_t)bl * N_NODES + n0 + l15) * DIM + q * 8;
    v8s a0 = *reinterpret_cast<const v8s*>(yrow);
    v8s a1 = *reinterpret_cast<const v8s*>(yrow + 32);
    v8s a2 = *reinterpret_cast<const v8s*>(yrow + 64);
    v8s a3 = *reinterpret_cast<const v8s*>(yrow + 96);

    v4f acc[8];
    #pragma unroll
    for (int ft = 0; ft < 8; ft++) acc[ft] = (v4f){0.f,0.f,0.f,0.f};
    #pragma unroll
    for (int ft = 0; ft < 8; ft++) acc[ft] = __builtin_amdgcn_mfma_f32_16x16x32_bf16(a0, bfr[0][ft], acc[ft], 0, 0, 0);
    #pragma unroll
    for (int ft = 0; ft < 8; ft++) acc[ft] = __builtin_amdgcn_mfma_f32_16x16x32_bf16(a1, bfr[1][ft], acc[ft], 0, 0, 0);
    #pragma unroll
    for (int ft = 0; ft < 8; ft++) acc[ft] = __builtin_amdgcn_mfma_f32_16x16x32_bf16(a2, bfr[2][ft], acc[ft], 0, 0, 0);
    #pragma unroll
    for (int ft = 0; ft < 8; ft++) acc[ft] = __builtin_amdgcn_mfma_f32_16x16x32_bf16(a3, bfr[3][ft], acc[ft], 0, 0, 0);

    // epilogue: + b1, relu, * c[row], accumulate. D: row = n0 + q*4 + r, col = ft*16 + l15
    float4 cvv = *reinterpret_cast<const float4*>(cw + n0 + q * 4);
    float cvr[4] = {cvv.x, cvv.y, cvv.z, cvv.w};
    #pragma unroll
    for (int ft = 0; ft < 8; ft++){
      #pragma unroll
      for (int r = 0; r < 4; r++){
        float v = acc[ft][r] + b1v[ft];
        v = fmaxf(v, 0.0f);
        sacc[ft] = fmaf(v, cvr[r], sacc[ft]);
      }
    }
  }

  // reduce over q-groups (rows) -> col sums, then one atomic per (f)
  #pragma unroll
  for (int ft = 0; ft < 8; ft++){
    float v = sacc[ft];
    v += __shfl_xor(v, 16);
    v += __shfl_xor(v, 32);
    if (lane < 16) atomicAdd(&S[(b_global0 + bl) * DIM + ft * 16 + lane], v);
  }
}

// ---------------- final: out[b,f] = (S[b,:]/N)·W2[:,f] + b2[f] ----------------
__global__ void k_final(const float* __restrict__ S, const float* __restrict__ W2,
                        const float* __restrict__ b2, float* __restrict__ out){
  int i = blockIdx.x * 256 + threadIdx.x;
  if (i >= N_BATCH * DIM) return;
  int b = i >> 7, f = i & 127;
  float o = 0.0f;
  const float invN = 1.0f / (float)N_NODES;
  #pragma unroll 4
  for (int k = 0; k < 128; k++)
    o = fmaf(S[b * 128 + k], W2[k * 128 + f], o);
  out[i] = fmaf(o, invN, b2[f]);
}

// ---------------- host ----------------

extern "C" void kernel_launch(void* const* d_in, const int* in_sizes, int n_in,
                              void* d_out, int out_size, void* d_ws, size_t ws_size,
                              hipStream_t stream){
  const float* gene = (const float*)d_in[0];
  const int*   ei   = (const int*)d_in[1];
  const float* W1   = (const float*)d_in[2];
  const float* b1   = (const float*)d_in[3];
  const float* W2   = (const float*)d_in[4];
  const float* b2   = (const float*)d_in[5];
  float* out = (float*)d_out;

  char* base = (char*)d_ws;
  size_t off = 0;
  auto take = [&](size_t bytes)->char*{
    char* p = base + off;
    off = (off + bytes + 255) & ~(size_t)255;
    return p;
  };

  // zero zone: hist (N+1) | cursor (N) | S (B*128 f32)  -- one contiguous zero pass
  const int ZWORDS = (N_NODES + 1) + N_NODES + N_BATCH * DIM;
  uint32_t* zzone  = (uint32_t*)take((size_t)ZWORDS * 4);
  uint32_t* hist   = zzone;
  uint32_t* cursor = zzone + (N_NODES + 1);
  float*    S      = (float*)(zzone + (N_NODES + 1) + N_NODES);

  uint32_t* row_start = (uint32_t*)take((size_t)N_NODES * 4);
  float*    dinv      = (float*)take((size_t)N_NODES * 4);
  float*    cw        = (float*)take((size_t)N_NODES * 4);
  int2*     emeta     = (int2*)take((size_t)N_EDGES * 8);
  uint16_t* W1P       = (uint16_t*)take((size_t)16 * 128 * 8 * 2);

  // batch-chunked x/y bf16 buffers sized to fit ws
  const size_t per_batch = (size_t)N_NODES * DIM * 2;   // 5.12 MB
  size_t remain = (ws_size > off) ? (ws_size - off) : 0;
  int C = (int)(remain / (2 * per_batch));
  if (C < 1) C = 1;
  if (C > N_BATCH) C = N_BATCH;
  uint32_t* xb = (uint32_t*)take(per_batch * C);
  uint32_t* yb = (uint32_t*)take(per_batch * C);

  k_zero<<<cdiv(ZWORDS, 256), 256, 0, stream>>>(zzone, ZWORDS);
  k_hist<<<cdiv(N_EDGES, 256), 256, 0, stream>>>(ei, hist);
  k_scan<<<1, 1024, 0, stream>>>(hist, row_start, dinv, cw);
  k_edge<<<cdiv(N_EDGES, 256), 256, 0, stream>>>(ei, row_start, cursor, dinv, cw, emeta);
  k_w1pack<<<64, 256, 0, stream>>>(W1, W1P);

  for (int b0 = 0; b0 < N_BATCH; b0 += C){
    int Cb = (N_BATCH - b0 < C) ? (N_BATCH - b0) : C;
    int nu = Cb * N_NODES * (DIM / 2);
    k_cvt<<<cdiv(nu, 2048), 256, 0, stream>>>(((const float2*)gene) + (size_t)b0 * N_NODES * (DIM / 2), xb, nu);
    k_agg<<<dim3(N_NODES / 4, Cb), 256, 0, stream>>>(xb, yb, emeta, row_start, hist, dinv);
    k_gemm<<<dim3(cdiv(N_NODES / 16, 32), Cb), 256, 0, stream>>>((const uint16_t*)yb, W1P, b1, cw, S, b0);
  }

  k_final<<<cdiv(N_BATCH * DIM, 256), 256, 0, stream>>>(S, W2, b2, out);
}

// Round 6
// 508.600 us; speedup vs baseline: 1.6539x; 1.1137x over previous
//
#include <hip/hip_runtime.h>
#include <stdint.h>

#define N_NODES 20000
#define N_EDGES 320000
#define N_BATCH 32
#define DIM     128

typedef short v8s __attribute__((ext_vector_type(8)));
typedef float v4f __attribute__((ext_vector_type(4)));

static inline int cdiv(int a, int b){ return (a + b - 1) / b; }

__device__ __forceinline__ float bf_lo(uint32_t u){ return __uint_as_float(u << 16); }
__device__ __forceinline__ float bf_hi(uint32_t u){ return __uint_as_float(u & 0xffff0000u); }
__device__ __forceinline__ uint32_t f2bf(float f){            // RNE bf16 (finite inputs)
  uint32_t x = __float_as_uint(f);
  return (x + 0x7fffu + ((x >> 16) & 1u)) >> 16;
}
__device__ __forceinline__ uint32_t packbf2(float a, float b){ return f2bf(a) | (f2bf(b) << 16); }
__device__ __forceinline__ uint32_t cvtpk_bf16(float lo, float hi){   // RNE, 1 instr
  uint32_t r;
  asm volatile("v_cvt_pk_bf16_f32 %0, %1, %2" : "=v"(r) : "v"(lo), "v"(hi));
  return r;
}

// ---------------- setup kernels ----------------

__global__ void k_zero(uint32_t* p, int n){
  int i = blockIdx.x * 256 + threadIdx.x;
  if (i < n) p[i] = 0u;
}

__global__ void k_hist(const int* __restrict__ ei, uint32_t* __restrict__ hist){
  int e = blockIdx.x * 256 + threadIdx.x;
  if (e < N_EDGES){
    int d = ei[N_EDGES + e];
    atomicAdd(&hist[d], 1u);
  }
}

// single-block exclusive scan of hist -> row_start; also deg-derived dinv, c-init
__global__ void k_scan(const uint32_t* __restrict__ hist, uint32_t* __restrict__ row_start,
                       float* __restrict__ dinv, float* __restrict__ cw){
  __shared__ uint32_t part[1024];
  const int t = threadIdx.x;
  const int base = t * 20;                       // 1024*20 = 20480 >= 20000
  uint32_t cnt[20];
  uint32_t s = 0;
  #pragma unroll
  for (int i = 0; i < 20; i++){
    int idx = base + i;
    uint32_t v = (idx < N_NODES) ? hist[idx] : 0u;
    cnt[i] = v; s += v;
  }
  part[t] = s;
  __syncthreads();
  for (int off = 1; off < 1024; off <<= 1){      // inclusive Hillis-Steele
    uint32_t v = part[t];
    uint32_t add = (t >= off) ? part[t - off] : 0u;
    __syncthreads();
    part[t] = v + add;
    __syncthreads();
  }
  uint32_t run = (t > 0) ? part[t - 1] : 0u;     // exclusive prefix
  #pragma unroll
  for (int i = 0; i < 20; i++){
    int idx = base + i;
    if (idx < N_NODES){
      row_start[idx] = run;
      float deg = (float)cnt[i] + 1.0f;
      dinv[idx] = rsqrtf(deg);
      cw[idx]   = 1.0f / deg;                    // self_norm; edge terms added by k_edge
      run += cnt[i];
    }
  }
}

// emeta.x = src * 256 (byte offset of src row in a batch slab), emeta.y = f32 weight bits
__global__ void k_edge(const int* __restrict__ ei, const uint32_t* __restrict__ row_start,
                       uint32_t* __restrict__ cursor, const float* __restrict__ dinv,
                       float* __restrict__ cw, int2* __restrict__ emeta){
  int e = blockIdx.x * 256 + threadIdx.x;
  if (e >= N_EDGES) return;
  int s = ei[e];
  int d = ei[N_EDGES + e];
  float w = dinv[s] * dinv[d];
  atomicAdd(&cw[s], w);
  uint32_t off = atomicAdd(&cursor[d], 1u);
  uint32_t pos = row_start[d] + off;
  emeta[pos] = make_int2(s << 8, __float_as_int(w));
}

// W1 fp32 [k][f] -> bf16 frag-packed: W1P[((k>>3)*128 + f)*8 + (k&7)]
__global__ void k_w1pack(const float* __restrict__ W1, uint16_t* __restrict__ W1P){
  int i = blockIdx.x * 256 + threadIdx.x;
  if (i >= 16 * 128 * 8) return;
  int e = i & 7, f = (i >> 3) & 127, q = i >> 10;
  int k = q * 8 + e;
  W1P[i] = (uint16_t)f2bf(W1[k * 128 + f]);
}

// fp32 -> packed bf16 (2 per u32), grid-stride
__global__ void k_cvt(const float2* __restrict__ x, uint32_t* __restrict__ xb, int n_u32){
  int i = blockIdx.x * 256 + threadIdx.x;
  int stride = gridDim.x * 256;
  for (; i < n_u32; i += stride){
    float2 v = x[i];
    xb[i] = packbf2(v.x, v.y);
  }
}

// ---------------- phase A: y = (A_hat x), bf16 in/out, fp32 accum ----------------
// one wave per (dst node, batch). dwordx4 gathers: 16 lanes cover one 256B feature
// row; the 4 lane-groups (g = lane>>4) each handle a DIFFERENT edge -> 4 edges per
// wave-load. Edge meta chunk-loaded (64 edges) then bpermute-broadcast. 4-deep
// static software pipeline (16 edges / 4KB in flight per wave). Tail steps are
// uniform-branch guarded; intra-step padding via zero weights + clamped src.
__global__ __launch_bounds__(256) void k_agg(const uint32_t* __restrict__ xb, uint32_t* __restrict__ yb,
                      const int2* __restrict__ emeta, const uint32_t* __restrict__ row_start,
                      const uint32_t* __restrict__ hist, const float* __restrict__ dinv){
  const int wv = threadIdx.x >> 6, lane = threadIdx.x & 63;
  const int g = lane >> 4, s = lane & 15;
  int n = blockIdx.x * 4 + wv;
  if (n >= N_NODES) return;
  const uint32_t bl = blockIdx.y;
  const char* xbase = (const char*)xb + (size_t)bl * ((size_t)N_NODES * 256);
  const uint32_t s16 = (uint32_t)s * 16u;

  float alo0=0.f, ahi0=0.f, alo1=0.f, ahi1=0.f;
  float alo2=0.f, ahi2=0.f, alo3=0.f, ahi3=0.f;

#define CONS(VV, WW) do { \
    alo0 = fmaf((WW), bf_lo((VV).x), alo0); ahi0 = fmaf((WW), bf_hi((VV).x), ahi0); \
    alo1 = fmaf((WW), bf_lo((VV).y), alo1); ahi1 = fmaf((WW), bf_hi((VV).y), ahi1); \
    alo2 = fmaf((WW), bf_lo((VV).z), alo2); ahi2 = fmaf((WW), bf_hi((VV).z), ahi2); \
    alo3 = fmaf((WW), bf_lo((VV).w), alo3); ahi3 = fmaf((WW), bf_hi((VV).w), ahi3); \
  } while(0)

#define PREP(P, VV, WW) do { \
    uint32_t idx_ = sbase + (P)*4u + (uint32_t)g; \
    uint32_t ci_  = (idx_ < lim) ? idx_ : (lim - 1u); \
    uint32_t so_  = (uint32_t)__shfl(mx, (int)ci_); \
    float    wf_  = __int_as_float(__shfl(my, (int)ci_)); \
    WW = (idx_ < lim) ? wf_ : 0.0f; \
    VV = *reinterpret_cast<const uint4*>(xbase + (so_ + s16)); \
  } while(0)

  // self term: all 4 groups load the same row (HW broadcasts), weight self/4
  float di = dinv[n];
  {
    uint4 sv = *reinterpret_cast<const uint4*>(xbase + ((uint32_t)n * 256u + s16));
    float wself = di * di * 0.25f;
    CONS(sv, wself);
  }

  uint32_t rs  = (uint32_t)__builtin_amdgcn_readfirstlane((int)row_start[n]);
  uint32_t cnt = (uint32_t)__builtin_amdgcn_readfirstlane((int)hist[n]);

  for (uint32_t cbase = 0; cbase < cnt; cbase += 64u){
    uint32_t lim = cnt - cbase; if (lim > 64u) lim = 64u;   // edges in this chunk, >=1
    uint32_t cl = (uint32_t)lane; if (cl >= lim) cl = lim - 1u;
    int2 m = emeta[rs + cbase + cl];                        // one coalesced 512B load
    int mx = m.x, my = m.y;

    uint32_t sbase = 0;
    while (sbase + 16u <= lim){                             // full 16-edge super-steps
      uint4 p0, p1, p2, p3; float q0, q1, q2, q3;
      PREP(0, p0, q0); PREP(1, p1, q1); PREP(2, p2, q2); PREP(3, p3, q3);
      CONS(p0, q0); CONS(p1, q1); CONS(p2, q2); CONS(p3, q3);
      sbase += 16u;
    }
    if (sbase < lim){                                       // tail: 1..15 edges
      uint32_t live = lim - sbase;
      uint4 p0, p1, p2, p3; float q0, q1, q2, q3;
      PREP(0, p0, q0);
      if (live > 4u)  { PREP(1, p1, q1); }
      if (live > 8u)  { PREP(2, p2, q2); }
      if (live > 12u) { PREP(3, p3, q3); }
      CONS(p0, q0);
      if (live > 4u)  { CONS(p1, q1); }
      if (live > 8u)  { CONS(p2, q2); }
      if (live > 12u) { CONS(p3, q3); }
    }
  }
#undef PREP
#undef CONS

  // reduce over the 4 edge-groups: lanes {s, s+16, s+32, s+48} hold same features
  alo0 += __shfl_xor(alo0, 16); alo0 += __shfl_xor(alo0, 32);
  ahi0 += __shfl_xor(ahi0, 16); ahi0 += __shfl_xor(ahi0, 32);
  alo1 += __shfl_xor(alo1, 16); alo1 += __shfl_xor(alo1, 32);
  ahi1 += __shfl_xor(ahi1, 16); ahi1 += __shfl_xor(ahi1, 32);
  alo2 += __shfl_xor(alo2, 16); alo2 += __shfl_xor(alo2, 32);
  ahi2 += __shfl_xor(ahi2, 16); ahi2 += __shfl_xor(ahi2, 32);
  alo3 += __shfl_xor(alo3, 16); alo3 += __shfl_xor(alo3, 32);
  ahi3 += __shfl_xor(ahi3, 16); ahi3 += __shfl_xor(ahi3, 32);

  if (lane < 16){
    uint4 o;
    o.x = cvtpk_bf16(alo0, ahi0);
    o.y = cvtpk_bf16(alo1, ahi1);
    o.z = cvtpk_bf16(alo2, ahi2);
    o.w = cvtpk_bf16(alo3, ahi3);
    char* ybase = (char*)yb + (size_t)bl * ((size_t)N_NODES * 256);
    *reinterpret_cast<uint4*>(ybase + ((uint32_t)n * 256u + s16)) = o;
  }
}

// ---------------- phase B: S[b,f] += sum_n c[n]*relu(y[b,n,:]·W1[:,f] + b1[f]) ----------------
// 4 waves/block; each wave: W1 fully in registers (32 B-frags), loops 8 n-tiles of 16 rows
__global__ __launch_bounds__(256) void k_gemm(const uint16_t* __restrict__ y,
                                              const uint16_t* __restrict__ W1P,
                                              const float* __restrict__ b1,
                                              const float* __restrict__ cw,
                                              float* __restrict__ S, int b_global0){
  const int w = threadIdx.x >> 6, lane = threadIdx.x & 63;
  const int l15 = lane & 15, q = lane >> 4;
  const int bl = blockIdx.y;

  // B-frags: lane l, elem e -> W1[k][ft*16 + l15], k = q32*32 + q*8 + e  (same k-map as A)
  v8s bfr[4][8];
  #pragma unroll
  for (int q32 = 0; q32 < 4; q32++)
    #pragma unroll
    for (int ft = 0; ft < 8; ft++)
      bfr[q32][ft] = *reinterpret_cast<const v8s*>(W1P + ((q32 * 4 + q) * 128 + ft * 16 + l15) * 8);

  float b1v[8];
  #pragma unroll
  for (int ft = 0; ft < 8; ft++) b1v[ft] = b1[ft * 16 + l15];

  float sacc[8] = {0.f,0.f,0.f,0.f,0.f,0.f,0.f,0.f};

  const int NT = N_NODES / 16;                   // 1250 full tiles
  int tile0 = (blockIdx.x * 4 + w) * 8;
  for (int t = 0; t < 8; t++){
    int tile = tile0 + t;
    if (tile >= NT) break;
    int n0 = tile * 16;
    const uint16_t* yrow = y + ((size_t)bl * N_NODES + n0 + l15) * DIM + q * 8;
    v8s a0 = *reinterpret_cast<const v8s*>(yrow);
    v8s a1 = *reinterpret_cast<const v8s*>(yrow + 32);
    v8s a2 = *reinterpret_cast<const v8s*>(yrow + 64);
    v8s a3 = *reinterpret_cast<const v8s*>(yrow + 96);

    v4f acc[8];
    #pragma unroll
    for (int ft = 0; ft < 8; ft++) acc[ft] = (v4f){0.f,0.f,0.f,0.f};
    #pragma unroll
    for (int ft = 0; ft < 8; ft++) acc[ft] = __builtin_amdgcn_mfma_f32_16x16x32_bf16(a0, bfr[0][ft], acc[ft], 0, 0, 0);
    #pragma unroll
    for (int ft = 0; ft < 8; ft++) acc[ft] = __builtin_amdgcn_mfma_f32_16x16x32_bf16(a1, bfr[1][ft], acc[ft], 0, 0, 0);
    #pragma unroll
    for (int ft = 0; ft < 8; ft++) acc[ft] = __builtin_amdgcn_mfma_f32_16x16x32_bf16(a2, bfr[2][ft], acc[ft], 0, 0, 0);
    #pragma unroll
    for (int ft = 0; ft < 8; ft++) acc[ft] = __builtin_amdgcn_mfma_f32_16x16x32_bf16(a3, bfr[3][ft], acc[ft], 0, 0, 0);

    // epilogue: + b1, relu, * c[row], accumulate. D: row = n0 + q*4 + r, col = ft*16 + l15
    float4 cvv = *reinterpret_cast<const float4*>(cw + n0 + q * 4);
    float cvr[4] = {cvv.x, cvv.y, cvv.z, cvv.w};
    #pragma unroll
    for (int ft = 0; ft < 8; ft++){
      #pragma unroll
      for (int r = 0; r < 4; r++){
        float v = acc[ft][r] + b1v[ft];
        v = fmaxf(v, 0.0f);
        sacc[ft] = fmaf(v, cvr[r], sacc[ft]);
      }
    }
  }

  // reduce over q-groups (rows) -> col sums, then one atomic per (f)
  #pragma unroll
  for (int ft = 0; ft < 8; ft++){
    float v = sacc[ft];
    v += __shfl_xor(v, 16);
    v += __shfl_xor(v, 32);
    if (lane < 16) atomicAdd(&S[(b_global0 + bl) * DIM + ft * 16 + lane], v);
  }
}

// ---------------- final: out[b,f] = (S[b,:]/N)·W2[:,f] + b2[f] ----------------
__global__ void k_final(const float* __restrict__ S, const float* __restrict__ W2,
                        const float* __restrict__ b2, float* __restrict__ out){
  int i = blockIdx.x * 256 + threadIdx.x;
  if (i >= N_BATCH * DIM) return;
  int b = i >> 7, f = i & 127;
  float o = 0.0f;
  const float invN = 1.0f / (float)N_NODES;
  #pragma unroll 4
  for (int k = 0; k < 128; k++)
    o = fmaf(S[b * 128 + k], W2[k * 128 + f], o);
  out[i] = fmaf(o, invN, b2[f]);
}

// ---------------- host ----------------

extern "C" void kernel_launch(void* const* d_in, const int* in_sizes, int n_in,
                              void* d_out, int out_size, void* d_ws, size_t ws_size,
                              hipStream_t stream){
  const float* gene = (const float*)d_in[0];
  const int*   ei   = (const int*)d_in[1];
  const float* W1   = (const float*)d_in[2];
  const float* b1   = (const float*)d_in[3];
  const float* W2   = (const float*)d_in[4];
  const float* b2   = (const float*)d_in[5];
  float* out = (float*)d_out;

  char* base = (char*)d_ws;
  size_t off = 0;
  auto take = [&](size_t bytes)->char*{
    char* p = base + off;
    off = (off + bytes + 255) & ~(size_t)255;
    return p;
  };

  // zero zone: hist (N+1) | cursor (N) | S (B*128 f32)  -- one contiguous zero pass
  const int ZWORDS = (N_NODES + 1) + N_NODES + N_BATCH * DIM;
  uint32_t* zzone  = (uint32_t*)take((size_t)ZWORDS * 4);
  uint32_t* hist   = zzone;
  uint32_t* cursor = zzone + (N_NODES + 1);
  float*    S      = (float*)(zzone + (N_NODES + 1) + N_NODES);

  uint32_t* row_start = (uint32_t*)take((size_t)N_NODES * 4);
  float*    dinv      = (float*)take((size_t)N_NODES * 4);
  float*    cw        = (float*)take((size_t)N_NODES * 4);
  int2*     emeta     = (int2*)take((size_t)N_EDGES * 8);
  uint16_t* W1P       = (uint16_t*)take((size_t)16 * 128 * 8 * 2);

  // batch-chunked x/y bf16 buffers sized to fit ws
  const size_t per_batch = (size_t)N_NODES * DIM * 2;   // 5.12 MB
  size_t remain = (ws_size > off) ? (ws_size - off) : 0;
  int C = (int)(remain / (2 * per_batch));
  if (C < 1) C = 1;
  if (C > N_BATCH) C = N_BATCH;
  uint32_t* xb = (uint32_t*)take(per_batch * C);
  uint32_t* yb = (uint32_t*)take(per_batch * C);

  k_zero<<<cdiv(ZWORDS, 256), 256, 0, stream>>>(zzone, ZWORDS);
  k_hist<<<cdiv(N_EDGES, 256), 256, 0, stream>>>(ei, hist);
  k_scan<<<1, 1024, 0, stream>>>(hist, row_start, dinv, cw);
  k_edge<<<cdiv(N_EDGES, 256), 256, 0, stream>>>(ei, row_start, cursor, dinv, cw, emeta);
  k_w1pack<<<64, 256, 0, stream>>>(W1, W1P);

  for (int b0 = 0; b0 < N_BATCH; b0 += C){
    int Cb = (N_BATCH - b0 < C) ? (N_BATCH - b0) : C;
    int nu = Cb * N_NODES * (DIM / 2);
    k_cvt<<<cdiv(nu, 2048), 256, 0, stream>>>(((const float2*)gene) + (size_t)b0 * N_NODES * (DIM / 2), xb, nu);
    k_agg<<<dim3(N_NODES / 4, Cb), 256, 0, stream>>>(xb, yb, emeta, row_start, hist, dinv);
    k_gemm<<<dim3(cdiv(N_NODES / 16, 32), Cb), 256, 0, stream>>>((const uint16_t*)yb, W1P, b1, cw, S, b0);
  }

  k_final<<<cdiv(N_BATCH * DIM, 256), 256, 0, stream>>>(S, W2, b2, out);
}

// Round 9
// 493.900 us; speedup vs baseline: 1.7032x; 1.0298x over previous
//
#include <hip/hip_runtime.h>
#include <stdint.h>

#define N_NODES 20000
#define N_EDGES 320000
#define N_BATCH 32
#define DIM     128

typedef _Float16 v8h __attribute__((ext_vector_type(8)));
typedef float v4f __attribute__((ext_vector_type(4)));

static inline int cdiv(int a, int b){ return (a + b - 1) / b; }

// pack two f32 -> two f16 (RTZ), single v_cvt_pkrtz_f16_f32 (GCN-era instr)
__device__ __forceinline__ uint32_t pk_f16(float lo, float hi){
  auto h = __builtin_amdgcn_cvt_pkrtz(lo, hi);   // __fp16 ext_vector(2)
  return __builtin_bit_cast(uint32_t, h);
}
// acc += f32(f16 from lo/hi half of u) * w  -- single v_fma_mix_f32 (gfx906+)
__device__ __forceinline__ void fmix_lo(float& acc, uint32_t u, float w){
  asm("v_fma_mix_f32 %0, %1, %2, %0 op_sel:[0,0,0] op_sel_hi:[1,0,0]"
      : "+v"(acc) : "v"(u), "v"(w));
}
__device__ __forceinline__ void fmix_hi(float& acc, uint32_t u, float w){
  asm("v_fma_mix_f32 %0, %1, %2, %0 op_sel:[1,0,0] op_sel_hi:[1,0,0]"
      : "+v"(acc) : "v"(u), "v"(w));
}

// ---------------- setup kernels ----------------

__global__ void k_zero(uint32_t* p, int n){
  int i = blockIdx.x * 256 + threadIdx.x;
  if (i < n) p[i] = 0u;
}

__global__ void k_hist(const int* __restrict__ ei, uint32_t* __restrict__ hist){
  int e = blockIdx.x * 256 + threadIdx.x;
  if (e < N_EDGES){
    int d = ei[N_EDGES + e];
    atomicAdd(&hist[d], 1u);
  }
}

// single-block exclusive scan of hist -> row_start; also deg-derived dinv, c-init
__global__ void k_scan(const uint32_t* __restrict__ hist, uint32_t* __restrict__ row_start,
                       float* __restrict__ dinv, float* __restrict__ cw){
  __shared__ uint32_t part[1024];
  const int t = threadIdx.x;
  const int base = t * 20;                       // 1024*20 = 20480 >= 20000
  uint32_t cnt[20];
  uint32_t s = 0;
  #pragma unroll
  for (int i = 0; i < 20; i++){
    int idx = base + i;
    uint32_t v = (idx < N_NODES) ? hist[idx] : 0u;
    cnt[i] = v; s += v;
  }
  part[t] = s;
  __syncthreads();
  for (int off = 1; off < 1024; off <<= 1){      // inclusive Hillis-Steele
    uint32_t v = part[t];
    uint32_t add = (t >= off) ? part[t - off] : 0u;
    __syncthreads();
    part[t] = v + add;
    __syncthreads();
  }
  uint32_t run = (t > 0) ? part[t - 1] : 0u;     // exclusive prefix
  #pragma unroll
  for (int i = 0; i < 20; i++){
    int idx = base + i;
    if (idx < N_NODES){
      row_start[idx] = run;
      float deg = (float)cnt[i] + 1.0f;
      dinv[idx] = rsqrtf(deg);
      cw[idx]   = 1.0f / deg;                    // self_norm; edge terms added by k_edge
      run += cnt[i];
    }
  }
}

// emeta.x = src * 256 (byte offset of src row in a batch slab), emeta.y = f32 weight bits
__global__ void k_edge(const int* __restrict__ ei, const uint32_t* __restrict__ row_start,
                       uint32_t* __restrict__ cursor, const float* __restrict__ dinv,
                       float* __restrict__ cw, int2* __restrict__ emeta){
  int e = blockIdx.x * 256 + threadIdx.x;
  if (e >= N_EDGES) return;
  int s = ei[e];
  int d = ei[N_EDGES + e];
  float w = dinv[s] * dinv[d];
  atomicAdd(&cw[s], w);
  uint32_t off = atomicAdd(&cursor[d], 1u);
  uint32_t pos = row_start[d] + off;
  emeta[pos] = make_int2(s << 8, __float_as_int(w));
}

// W1 fp32 [k][f] -> f16 frag-packed: W1P[((k>>3)*128 + f)*8 + (k&7)]
__global__ void k_w1pack(const float* __restrict__ W1, uint16_t* __restrict__ W1P){
  int i = blockIdx.x * 256 + threadIdx.x;
  if (i >= 16 * 128 * 8) return;
  int e = i & 7, f = (i >> 3) & 127, q = i >> 10;
  int k = q * 8 + e;
  W1P[i] = (uint16_t)(pk_f16(W1[k * 128 + f], 0.0f) & 0xffffu);
}

// fp32 -> packed f16: 32B read / 16B write per lane, cvt_pkrtz pack, grid-stride
__global__ void k_cvt(const float4* __restrict__ x, uint4* __restrict__ xb, int n_u4){
  int i = blockIdx.x * 256 + threadIdx.x;
  int stride = gridDim.x * 256;
  for (; i < n_u4; i += stride){
    float4 f0 = x[2 * i];
    float4 f1 = x[2 * i + 1];
    uint4 o;
    o.x = pk_f16(f0.x, f0.y);
    o.y = pk_f16(f0.z, f0.w);
    o.z = pk_f16(f1.x, f1.y);
    o.w = pk_f16(f1.z, f1.w);
    xb[i] = o;
  }
}

// ---------------- phase A: y = (A_hat x), f16 in/out, fp32 accum ----------------
// one wave per (dst node, batch). dwordx4 gathers: 16 lanes cover one 256B feature
// row; the 4 lane-groups (g = lane>>4) each handle a DIFFERENT edge -> 4 edges per
// wave-load. Edge meta chunk-loaded (64 edges) then bpermute-broadcast. 4-deep
// static software pipeline (16 edges / 4KB in flight per wave). Consume path uses
// v_fma_mix_f32 (1 instr per feature: f16 operand unpack fused into f32 FMA).
__global__ __launch_bounds__(256) void k_agg(const uint32_t* __restrict__ xb, uint32_t* __restrict__ yb,
                      const int2* __restrict__ emeta, const uint32_t* __restrict__ row_start,
                      const uint32_t* __restrict__ hist, const float* __restrict__ dinv){
  const int wv = threadIdx.x >> 6, lane = threadIdx.x & 63;
  const int g = lane >> 4, s = lane & 15;
  int n = blockIdx.x * 4 + wv;
  if (n >= N_NODES) return;
  const uint32_t bl = blockIdx.y;
  const char* xbase = (const char*)xb + (size_t)bl * ((size_t)N_NODES * 256);
  const uint32_t s16 = (uint32_t)s * 16u;

  float a0=0.f, a1=0.f, a2=0.f, a3=0.f, a4=0.f, a5=0.f, a6=0.f, a7=0.f;

#define CONS(VV, WW) do { \
    fmix_lo(a0, (VV).x, (WW)); fmix_hi(a1, (VV).x, (WW)); \
    fmix_lo(a2, (VV).y, (WW)); fmix_hi(a3, (VV).y, (WW)); \
    fmix_lo(a4, (VV).z, (WW)); fmix_hi(a5, (VV).z, (WW)); \
    fmix_lo(a6, (VV).w, (WW)); fmix_hi(a7, (VV).w, (WW)); \
  } while(0)

#define PREP(P, VV, WW) do { \
    uint32_t idx_ = sbase + (P)*4u + (uint32_t)g; \
    uint32_t ci_  = (idx_ < lim) ? idx_ : (lim - 1u); \
    uint32_t so_  = (uint32_t)__shfl(mx, (int)ci_); \
    float    wf_  = __int_as_float(__shfl(my, (int)ci_)); \
    WW = (idx_ < lim) ? wf_ : 0.0f; \
    VV = *reinterpret_cast<const uint4*>(xbase + (so_ + s16)); \
  } while(0)

  // self term: all 4 groups load the same row (HW broadcasts), weight self/4
  float di = dinv[n];
  {
    uint4 sv = *reinterpret_cast<const uint4*>(xbase + ((uint32_t)n * 256u + s16));
    float wself = di * di * 0.25f;
    CONS(sv, wself);
  }

  uint32_t rs  = (uint32_t)__builtin_amdgcn_readfirstlane((int)row_start[n]);
  uint32_t cnt = (uint32_t)__builtin_amdgcn_readfirstlane((int)hist[n]);

  for (uint32_t cbase = 0; cbase < cnt; cbase += 64u){
    uint32_t lim = cnt - cbase; if (lim > 64u) lim = 64u;   // edges in this chunk, >=1
    uint32_t cl = (uint32_t)lane; if (cl >= lim) cl = lim - 1u;
    int2 m = emeta[rs + cbase + cl];                        // one coalesced 512B load
    int mx = m.x, my = m.y;

    uint32_t sbase = 0;
    while (sbase + 16u <= lim){                             // full 16-edge super-steps
      uint4 p0, p1, p2, p3; float q0, q1, q2, q3;
      PREP(0, p0, q0); PREP(1, p1, q1); PREP(2, p2, q2); PREP(3, p3, q3);
      CONS(p0, q0); CONS(p1, q1); CONS(p2, q2); CONS(p3, q3);
      sbase += 16u;
    }
    if (sbase < lim){                                       // tail: 1..15 edges
      uint32_t live = lim - sbase;
      uint4 p0, p1, p2, p3; float q0, q1, q2, q3;
      PREP(0, p0, q0);
      if (live > 4u)  { PREP(1, p1, q1); }
      if (live > 8u)  { PREP(2, p2, q2); }
      if (live > 12u) { PREP(3, p3, q3); }
      CONS(p0, q0);
      if (live > 4u)  { CONS(p1, q1); }
      if (live > 8u)  { CONS(p2, q2); }
      if (live > 12u) { CONS(p3, q3); }
    }
  }
#undef PREP
#undef CONS

  // reduce over the 4 edge-groups: lanes {s, s+16, s+32, s+48} hold same features
  a0 += __shfl_xor(a0, 16); a0 += __shfl_xor(a0, 32);
  a1 += __shfl_xor(a1, 16); a1 += __shfl_xor(a1, 32);
  a2 += __shfl_xor(a2, 16); a2 += __shfl_xor(a2, 32);
  a3 += __shfl_xor(a3, 16); a3 += __shfl_xor(a3, 32);
  a4 += __shfl_xor(a4, 16); a4 += __shfl_xor(a4, 32);
  a5 += __shfl_xor(a5, 16); a5 += __shfl_xor(a5, 32);
  a6 += __shfl_xor(a6, 16); a6 += __shfl_xor(a6, 32);
  a7 += __shfl_xor(a7, 16); a7 += __shfl_xor(a7, 32);

  if (lane < 16){
    uint4 o;
    o.x = pk_f16(a0, a1);
    o.y = pk_f16(a2, a3);
    o.z = pk_f16(a4, a5);
    o.w = pk_f16(a6, a7);
    char* ybase = (char*)yb + (size_t)bl * ((size_t)N_NODES * 256);
    *reinterpret_cast<uint4*>(ybase + ((uint32_t)n * 256u + s16)) = o;
  }
}

// ---------------- phase B: S[b,f] += sum_n c[n]*relu(y[b,n,:]·W1[:,f] + b1[f]) ----------------
// 4 waves/block; each wave: W1 fully in registers (32 B-frags), loops 8 n-tiles of 16 rows
__global__ __launch_bounds__(256) void k_gemm(const uint16_t* __restrict__ y,
                                              const uint16_t* __restrict__ W1P,
                                              const float* __restrict__ b1,
                                              const float* __restrict__ cw,
                                              float* __restrict__ S, int b_global0){
  const int w = threadIdx.x >> 6, lane = threadIdx.x & 63;
  const int l15 = lane & 15, q = lane >> 4;
  const int bl = blockIdx.y;

  // B-frags: lane l, elem e -> W1[k][ft*16 + l15], k = q32*32 + q*8 + e  (same k-map as A)
  v8h bfr[4][8];
  #pragma unroll
  for (int q32 = 0; q32 < 4; q32++)
    #pragma unroll
    for (int ft = 0; ft < 8; ft++)
      bfr[q32][ft] = *reinterpret_cast<const v8h*>(W1P + ((q32 * 4 + q) * 128 + ft * 16 + l15) * 8);

  float b1v[8];
  #pragma unroll
  for (int ft = 0; ft < 8; ft++) b1v[ft] = b1[ft * 16 + l15];

  float sacc[8] = {0.f,0.f,0.f,0.f,0.f,0.f,0.f,0.f};

  const int NT = N_NODES / 16;                   // 1250 full tiles
  int tile0 = (blockIdx.x * 4 + w) * 8;
  for (int t = 0; t < 8; t++){
    int tile = tile0 + t;
    if (tile >= NT) break;
    int n0 = tile * 16;
    const uint16_t* yrow = y + ((size_t)bl * N_NODES + n0 + l15) * DIM + q * 8;
    v8h a0 = *reinterpret_cast<const v8h*>(yrow);
    v8h a1 = *reinterpret_cast<const v8h*>(yrow + 32);
    v8h a2 = *reinterpret_cast<const v8h*>(yrow + 64);
    v8h a3 = *reinterpret_cast<const v8h*>(yrow + 96);

    v4f acc[8];
    #pragma unroll
    for (int ft = 0; ft < 8; ft++) acc[ft] = (v4f){0.f,0.f,0.f,0.f};
    #pragma unroll
    for (int ft = 0; ft < 8; ft++) acc[ft] = __builtin_amdgcn_mfma_f32_16x16x32_f16(a0, bfr[0][ft], acc[ft], 0, 0, 0);
    #pragma unroll
    for (int ft = 0; ft < 8; ft++) acc[ft] = __builtin_amdgcn_mfma_f32_16x16x32_f16(a1, bfr[1][ft], acc[ft], 0, 0, 0);
    #pragma unroll
    for (int ft = 0; ft < 8; ft++) acc[ft] = __builtin_amdgcn_mfma_f32_16x16x32_f16(a2, bfr[2][ft], acc[ft], 0, 0, 0);
    #pragma unroll
    for (int ft = 0; ft < 8; ft++) acc[ft] = __builtin_amdgcn_mfma_f32_16x16x32_f16(a3, bfr[3][ft], acc[ft], 0, 0, 0);

    // epilogue: + b1, relu, * c[row], accumulate. D: row = n0 + q*4 + r, col = ft*16 + l15
    float4 cvv = *reinterpret_cast<const float4*>(cw + n0 + q * 4);
    float cvr[4] = {cvv.x, cvv.y, cvv.z, cvv.w};
    #pragma unroll
    for (int ft = 0; ft < 8; ft++){
      #pragma unroll
      for (int r = 0; r < 4; r++){
        float v = acc[ft][r] + b1v[ft];
        v = fmaxf(v, 0.0f);
        sacc[ft] = fmaf(v, cvr[r], sacc[ft]);
      }
    }
  }

  // reduce over q-groups (rows) -> col sums, then one atomic per (f)
  #pragma unroll
  for (int ft = 0; ft < 8; ft++){
    float v = sacc[ft];
    v += __shfl_xor(v, 16);
    v += __shfl_xor(v, 32);
    if (lane < 16) atomicAdd(&S[(b_global0 + bl) * DIM + ft * 16 + lane], v);
  }
}

// ---------------- final: out[b,f] = (S[b,:]/N)·W2[:,f] + b2[f] ----------------
__global__ void k_final(const float* __restrict__ S, const float* __restrict__ W2,
                        const float* __restrict__ b2, float* __restrict__ out){
  int i = blockIdx.x * 256 + threadIdx.x;
  if (i >= N_BATCH * DIM) return;
  int b = i >> 7, f = i & 127;
  float o = 0.0f;
  const float invN = 1.0f / (float)N_NODES;
  #pragma unroll 4
  for (int k = 0; k < 128; k++)
    o = fmaf(S[b * 128 + k], W2[k * 128 + f], o);
  out[i] = fmaf(o, invN, b2[f]);
}

// ---------------- host ----------------

extern "C" void kernel_launch(void* const* d_in, const int* in_sizes, int n_in,
                              void* d_out, int out_size, void* d_ws, size_t ws_size,
                              hipStream_t stream){
  const float* gene = (const float*)d_in[0];
  const int*   ei   = (const int*)d_in[1];
  const float* W1   = (const float*)d_in[2];
  const float* b1   = (const float*)d_in[3];
  const float* W2   = (const float*)d_in[4];
  const float* b2   = (const float*)d_in[5];
  float* out = (float*)d_out;

  char* base = (char*)d_ws;
  size_t off = 0;
  auto take = [&](size_t bytes)->char*{
    char* p = base + off;
    off = (off + bytes + 255) & ~(size_t)255;
    return p;
  };

  // zero zone: hist (N+1) | cursor (N) | S (B*128 f32)  -- one contiguous zero pass
  const int ZWORDS = (N_NODES + 1) + N_NODES + N_BATCH * DIM;
  uint32_t* zzone  = (uint32_t*)take((size_t)ZWORDS * 4);
  uint32_t* hist   = zzone;
  uint32_t* cursor = zzone + (N_NODES + 1);
  float*    S      = (float*)(zzone + (N_NODES + 1) + N_NODES);

  uint32_t* row_start = (uint32_t*)take((size_t)N_NODES * 4);
  float*    dinv      = (float*)take((size_t)N_NODES * 4);
  float*    cw        = (float*)take((size_t)N_NODES * 4);
  int2*     emeta     = (int2*)take((size_t)N_EDGES * 8);
  uint16_t* W1P       = (uint16_t*)take((size_t)16 * 128 * 8 * 2);

  // batch-chunked x/y f16 buffers sized to fit ws
  const size_t per_batch = (size_t)N_NODES * DIM * 2;   // 5.12 MB
  size_t remain = (ws_size > off) ? (ws_size - off) : 0;
  int C = (int)(remain / (2 * per_batch));
  if (C < 1) C = 1;
  if (C > N_BATCH) C = N_BATCH;
  uint32_t* xb = (uint32_t*)take(per_batch * C);
  uint32_t* yb = (uint32_t*)take(per_batch * C);

  k_zero<<<cdiv(ZWORDS, 256), 256, 0, stream>>>(zzone, ZWORDS);
  k_hist<<<cdiv(N_EDGES, 256), 256, 0, stream>>>(ei, hist);
  k_scan<<<1, 1024, 0, stream>>>(hist, row_start, dinv, cw);
  k_edge<<<cdiv(N_EDGES, 256), 256, 0, stream>>>(ei, row_start, cursor, dinv, cw, emeta);
  k_w1pack<<<64, 256, 0, stream>>>(W1, W1P);

  for (int b0 = 0; b0 < N_BATCH; b0 += C){
    int Cb = (N_BATCH - b0 < C) ? (N_BATCH - b0) : C;
    int nu4 = Cb * N_NODES * (DIM / 8);
    int cvtb = cdiv(nu4, 256 * 8); if (cvtb > 2048) cvtb = 2048;
    k_cvt<<<cvtb, 256, 0, stream>>>(((const float4*)gene) + (size_t)b0 * N_NODES * (DIM / 4),
                                    (uint4*)xb, nu4);
    k_agg<<<dim3(N_NODES / 4, Cb), 256, 0, stream>>>(xb, yb, emeta, row_start, hist, dinv);
    k_gemm<<<dim3(cdiv(N_NODES / 16, 32), Cb), 256, 0, stream>>>((const uint16_t*)yb, W1P, b1, cw, S, b0);
  }

  k_final<<<cdiv(N_BATCH * DIM, 256), 256, 0, stream>>>(S, W2, b2, out);
}